// Round 1
// baseline (374.165 us; speedup 1.0000x reference)
//
#include <hip/hip_runtime.h>
#include <math.h>

#define B 32
#define NH 32
#define NKV 8
#define GRP 4
#define HD 128
#define DIM 4096
#define NQKV 6144   // (NH + 2*NKV) * HD
#define WIN 4096
#define KS 16       // split-K chunks for the skinny GEMMs
#define SPLIT 8     // attention sequence chunks
#define SCHUNK (WIN / SPLIT)   // 512 positions per chunk

// ---------------------------------------------------------------------------
// Skinny GEMM: part[kc][b][f] = sum_{k in chunk kc} X[b][k] * W[k][f]
// X: [B][K], W: [K][N]. Grid (N/256, KS), block 256. Deterministic split-K.
// ---------------------------------------------------------------------------
__global__ __launch_bounds__(256)
void gemv32_partial(const float* __restrict__ X, const float* __restrict__ W,
                    float* __restrict__ part, int K, int N) {
  const int f  = blockIdx.x * 256 + threadIdx.x;
  const int kc = blockIdx.y;
  const int kchunk = K / KS;
  const int k0 = kc * kchunk;

  // xs[kk][b], padded row to 36 floats (144B, 16B-aligned rows for float4 reads)
  __shared__ float xs[128][36];

  float acc[B];
#pragma unroll
  for (int b = 0; b < B; ++b) acc[b] = 0.f;

  for (int kb = 0; kb < kchunk; kb += 128) {
    __syncthreads();
    for (int idx = threadIdx.x; idx < B * 128; idx += 256) {
      int bb = idx >> 7;        // 0..31
      int kk = idx & 127;       // 0..127  (coalesced read from X)
      xs[kk][bb] = X[(size_t)bb * K + (k0 + kb + kk)];
    }
    __syncthreads();

    const float* wp = W + (size_t)(k0 + kb) * N + f;
#pragma unroll 4
    for (int kk = 0; kk < 128; ++kk) {
      float w = wp[(size_t)kk * N];                  // coalesced across lanes
      const float4* xr = (const float4*)&xs[kk][0];  // wave-uniform broadcast reads
#pragma unroll
      for (int b4 = 0; b4 < 8; ++b4) {
        float4 xv = xr[b4];
        acc[b4 * 4 + 0] += xv.x * w;
        acc[b4 * 4 + 1] += xv.y * w;
        acc[b4 * 4 + 2] += xv.z * w;
        acc[b4 * 4 + 3] += xv.w * w;
      }
    }
  }

  float* pp = part + (size_t)kc * B * N + f;
#pragma unroll
  for (int b = 0; b < B; ++b) pp[(size_t)b * N] = acc[b];
}

// ---------------------------------------------------------------------------
// Reduce split-K partials: out[idx] = sum_kc part[kc][idx]
// ---------------------------------------------------------------------------
__global__ __launch_bounds__(256)
void reduce_partials(const float* __restrict__ part, float* __restrict__ out,
                     int total) {
  int idx = blockIdx.x * 256 + threadIdx.x;
  if (idx >= total) return;
  float s = 0.f;
#pragma unroll
  for (int kc = 0; kc < KS; ++kc) s += part[(size_t)kc * total + idx];
  out[idx] = s;
}

// ---------------------------------------------------------------------------
// Rotary: per (b, head) vector v (128), out[e] = sum_d v[d] * rot[d][e]
// heads 0..31 -> q (scaled by 1/sqrt(128)), heads 32..39 -> k
// ---------------------------------------------------------------------------
__global__ __launch_bounds__(128)
void rotary_kernel(const float* __restrict__ xqkv, const float* __restrict__ rot,
                   float* __restrict__ qrot, float* __restrict__ krot) {
  const int b = blockIdx.x;
  const int h = blockIdx.y;   // 0..39
  const int e = threadIdx.x;  // 0..127

  __shared__ float vec[HD];
  vec[e] = xqkv[(size_t)b * NQKV + h * HD + e];
  __syncthreads();

  float s = 0.f;
#pragma unroll 8
  for (int d = 0; d < HD; ++d) s += vec[d] * rot[d * HD + e];

  if (h < NH) {
    qrot[((size_t)b * NH + h) * HD + e] = s * 0.08838834764831845f; // 1/sqrt(128)
  } else {
    krot[((size_t)b * NKV + (h - NH)) * HD + e] = s;
  }
}

// ---------------------------------------------------------------------------
// Flash-decode attention partial. Grid (B*NKV pairs, SPLIT chunks), block 256.
// Half-wave (32 lanes) owns one position at a time: coalesced float4 K/V rows.
// Online softmax with a single running max shared across the 4 group heads.
// ---------------------------------------------------------------------------
__global__ __launch_bounds__(256)
void attn_partial(const float* __restrict__ cache_k, const float* __restrict__ cache_v,
                  const float* __restrict__ qrot, const float* __restrict__ krot,
                  const float* __restrict__ xqkv, const int* __restrict__ start_pos,
                  float* __restrict__ o_part, float* __restrict__ ml_part) {
  const int pair = blockIdx.x;            // b * NKV + kvh
  const int b    = pair >> 3;
  const int kvh  = pair & 7;
  const int chunk = blockIdx.y;

  const int sp    = start_pos[0];
  const int cur   = sp & (WIN - 1);
  const int slice = (sp + 1 < WIN) ? (sp + 1) : WIN;

  const int tid  = threadIdx.x;
  const int wave = tid >> 6;
  const int lane = tid & 63;
  const int half = lane >> 5;
  const int l32  = lane & 31;
  const int hw   = wave * 2 + half;       // half-wave id 0..7

  // q fragments: lane holds d = l32*4 .. l32*4+3 for each of 4 group heads
  float4 q[GRP];
#pragma unroll
  for (int g = 0; g < GRP; ++g)
    q[g] = *(const float4*)(qrot + ((size_t)(b * NH + kvh * GRP + g)) * HD + l32 * 4);

  const float4* kbase = (const float4*)(cache_k + ((size_t)(kvh * B + b)) * WIN * HD);
  const float4* vbase = (const float4*)(cache_v + ((size_t)(kvh * B + b)) * WIN * HD);
  const float4 knew = *(const float4*)(krot + ((size_t)(b * NKV + kvh)) * HD + l32 * 4);
  const float4 vnew = *(const float4*)(xqkv + (size_t)b * NQKV + (NH + NKV + kvh) * HD + l32 * 4);

  float  m = -INFINITY;
  float  l[GRP] = {0.f, 0.f, 0.f, 0.f};
  float4 acc[GRP] = {};

  const int s0 = chunk * SCHUNK;
  int rem = slice - s0 - hw;
  int n_i = rem <= 0 ? 0 : ((rem + 7) >> 3);
  if (n_i > SCHUNK / 8) n_i = SCHUNK / 8;

#pragma unroll 2
  for (int i = 0; i < n_i; ++i) {
    const int p = s0 + i * 8 + hw;
    float4 k4, v4;
    if (p == cur) { k4 = knew; v4 = vnew; }
    else {
      k4 = kbase[(size_t)p * 32 + l32];
      v4 = vbase[(size_t)p * 32 + l32];
    }

    float s[GRP];
#pragma unroll
    for (int g = 0; g < GRP; ++g)
      s[g] = q[g].x * k4.x + q[g].y * k4.y + q[g].z * k4.z + q[g].w * k4.w;

    // reduce over the 32 lanes of the half-wave
#pragma unroll
    for (int off = 16; off > 0; off >>= 1) {
#pragma unroll
      for (int g = 0; g < GRP; ++g) s[g] += __shfl_xor(s[g], off);
    }

    float mn = fmaxf(fmaxf(s[0], s[1]), fmaxf(s[2], s[3]));
    if (mn > m) {
      float f = __expf(m - mn);   // m = -inf on first hit -> f = 0
#pragma unroll
      for (int g = 0; g < GRP; ++g) {
        l[g] *= f;
        acc[g].x *= f; acc[g].y *= f; acc[g].z *= f; acc[g].w *= f;
      }
      m = mn;
    }
#pragma unroll
    for (int g = 0; g < GRP; ++g) {
      float w = __expf(s[g] - m);
      l[g] += w;
      acc[g].x += w * v4.x; acc[g].y += w * v4.y;
      acc[g].z += w * v4.z; acc[g].w += w * v4.w;
    }
  }

  // combine the two halves of the wave (scale own by own factor, xor-add)
  {
    float m2 = __shfl_xor(m, 32);
    float mw = fmaxf(m, m2);
    float fs = (m == -INFINITY) ? 0.f : __expf(m - mw);
#pragma unroll
    for (int g = 0; g < GRP; ++g) {
      float t = l[g] * fs;
      l[g] = t + __shfl_xor(t, 32);
      float ax = acc[g].x * fs, ay = acc[g].y * fs, az = acc[g].z * fs, aw = acc[g].w * fs;
      acc[g].x = ax + __shfl_xor(ax, 32);
      acc[g].y = ay + __shfl_xor(ay, 32);
      acc[g].z = az + __shfl_xor(az, 32);
      acc[g].w = aw + __shfl_xor(aw, 32);
    }
    m = mw;
  }

  // combine the 4 waves via LDS
  __shared__ float red_m[4];
  __shared__ float red_l[4][GRP];
  __shared__ float red_o[4][GRP][HD];
  if (lane == 0) {
    red_m[wave] = m;
#pragma unroll
    for (int g = 0; g < GRP; ++g) red_l[wave][g] = l[g];
  }
  if (half == 0) {
#pragma unroll
    for (int g = 0; g < GRP; ++g)
      *(float4*)&red_o[wave][g][l32 * 4] = acc[g];
  }
  __syncthreads();

  float mstar = fmaxf(fmaxf(red_m[0], red_m[1]), fmaxf(red_m[2], red_m[3]));
  float fw[4];
#pragma unroll
  for (int w = 0; w < 4; ++w)
    fw[w] = (red_m[w] == -INFINITY) ? 0.f : __expf(red_m[w] - mstar);

  const size_t pc = (size_t)pair * SPLIT + chunk;
  for (int idx = tid; idx < GRP * HD; idx += 256) {
    int g = idx >> 7, d = idx & 127;
    float o = red_o[0][g][d] * fw[0] + red_o[1][g][d] * fw[1] +
              red_o[2][g][d] * fw[2] + red_o[3][g][d] * fw[3];
    o_part[(pc * GRP + g) * HD + d] = o;
  }
  if (tid < GRP) {
    float ls = red_l[0][tid] * fw[0] + red_l[1][tid] * fw[1] +
               red_l[2][tid] * fw[2] + red_l[3][tid] * fw[3];
    ml_part[(pc * GRP + tid) * 2 + 0] = mstar;
    ml_part[(pc * GRP + tid) * 2 + 1] = ls;
  }
}

// ---------------------------------------------------------------------------
// Combine the SPLIT chunk partials -> attn_out[b][n*128 + d]
// Grid: B*NH blocks, 128 threads (one per d).
// ---------------------------------------------------------------------------
__global__ __launch_bounds__(128)
void attn_combine(const float* __restrict__ o_part, const float* __restrict__ ml_part,
                  float* __restrict__ attn_out) {
  const int bid = blockIdx.x;   // b*32 + n
  const int b = bid >> 5, n = bid & 31;
  const int pair = b * NKV + (n >> 2);
  const int g = n & 3;
  const int d = threadIdx.x;

  float mc[SPLIT], lc[SPLIT];
  float mstar = -INFINITY;
#pragma unroll
  for (int c = 0; c < SPLIT; ++c) {
    size_t off = (((size_t)pair * SPLIT + c) * GRP + g) * 2;
    mc[c] = ml_part[off + 0];
    lc[c] = ml_part[off + 1];
    mstar = fmaxf(mstar, mc[c]);
  }
  float lsum = 0.f, osum = 0.f;
#pragma unroll
  for (int c = 0; c < SPLIT; ++c) {
    float f = (mc[c] == -INFINITY) ? 0.f : __expf(mc[c] - mstar);
    lsum += lc[c] * f;
    osum += o_part[(((size_t)pair * SPLIT + c) * GRP + g) * HD + d] * f;
  }
  attn_out[(size_t)b * DIM + n * HD + d] = osum / lsum;
}

// ---------------------------------------------------------------------------
extern "C" void kernel_launch(void* const* d_in, const int* in_sizes, int n_in,
                              void* d_out, int out_size, void* d_ws, size_t ws_size,
                              hipStream_t stream) {
  (void)in_sizes; (void)n_in; (void)out_size; (void)ws_size;

  const float* x    = (const float*)d_in[0];  // [1,1,32,4096]
  const float* wqkv = (const float*)d_in[1];  // [4096,6144]
  const float* wo   = (const float*)d_in[2];  // [4096,4096]
  const float* rot  = (const float*)d_in[3];  // [128,128]
  const float* ck   = (const float*)d_in[4];  // [8,32,4096,128]
  const float* cv   = (const float*)d_in[5];  // [8,32,4096,128]
  const int*   sp   = (const int*)d_in[6];    // scalar
  float* out = (float*)d_out;                 // [32,4096]

  float* ws       = (float*)d_ws;
  float* part     = ws;                                    // KS*B*NQKV = 3,145,728
  float* xqkv     = part + (size_t)KS * B * NQKV;          // 196,608
  float* qrot     = xqkv + (size_t)B * NQKV;               // 131,072
  float* krot     = qrot + (size_t)B * NH * HD;            // 32,768
  float* o_part   = krot + (size_t)B * NKV * HD;           // 1,048,576
  float* ml_part  = o_part + (size_t)B * NKV * SPLIT * GRP * HD;   // 16,384
  float* attn_out = ml_part + (size_t)B * NKV * SPLIT * GRP * 2;   // 131,072
  // total ~4.70M floats = ~18.8 MB of workspace

  // 1) xqkv = x @ wqkv  (split-K partials, then reduce)
  gemv32_partial<<<dim3(NQKV / 256, KS), 256, 0, stream>>>(x, wqkv, part, DIM, NQKV);
  reduce_partials<<<(B * NQKV) / 256, 256, 0, stream>>>(part, xqkv, B * NQKV);

  // 2) rotary on q (scaled) and k
  rotary_kernel<<<dim3(B, NH + NKV), 128, 0, stream>>>(xqkv, rot, qrot, krot);

  // 3) flash-decode attention over the KV cache (new token substituted in-flight)
  attn_partial<<<dim3(B * NKV, SPLIT), 256, 0, stream>>>(ck, cv, qrot, krot, xqkv,
                                                         sp, o_part, ml_part);
  attn_combine<<<B * NH, 128, 0, stream>>>(o_part, ml_part, attn_out);

  // 4) dense = attn_out @ wo
  gemv32_partial<<<dim3(DIM / 256, KS), 256, 0, stream>>>(attn_out, wo, part, DIM, DIM);
  reduce_partials<<<(B * DIM) / 256, 256, 0, stream>>>(part, out, B * DIM);
}

// Round 2
// 326.084 us; speedup vs baseline: 1.1474x; 1.1474x over previous
//
#include <hip/hip_runtime.h>
#include <math.h>

#define B 32
#define NH 32
#define NKV 8
#define GRP 4
#define HD 128
#define DIM 4096
#define NQKV 6144   // (NH + 2*NKV) * HD
#define WIN 4096
#define KS 32       // split-K chunks for the skinny GEMMs
#define SPLIT 8     // attention sequence chunks
#define SCHUNK (WIN / SPLIT)   // 512 positions per chunk

// ---------------------------------------------------------------------------
// Skinny GEMM: part[kc][b][f] = sum_{k in chunk kc} X[b][k] * W[k][f]
// X: [B][K], W: [K][N]. Grid (N/256, KS), block 256. Deterministic split-K.
// ---------------------------------------------------------------------------
__global__ __launch_bounds__(256)
void gemv32_partial(const float* __restrict__ X, const float* __restrict__ W,
                    float* __restrict__ part, int K, int N) {
  const int f  = blockIdx.x * 256 + threadIdx.x;
  const int kc = blockIdx.y;
  const int kchunk = K / KS;
  const int k0 = kc * kchunk;

  // xs[kk][b], padded row to 36 floats (144B, 16B-aligned rows for float4 reads)
  __shared__ float xs[128][36];

  float acc[B];
#pragma unroll
  for (int b = 0; b < B; ++b) acc[b] = 0.f;

  for (int kb = 0; kb < kchunk; kb += 128) {
    __syncthreads();
    for (int idx = threadIdx.x; idx < B * 128; idx += 256) {
      int bb = idx >> 7;        // 0..31
      int kk = idx & 127;       // 0..127  (coalesced read from X)
      xs[kk][bb] = X[(size_t)bb * K + (k0 + kb + kk)];
    }
    __syncthreads();

    const float* wp = W + (size_t)(k0 + kb) * N + f;
#pragma unroll 4
    for (int kk = 0; kk < 128; ++kk) {
      float w = wp[(size_t)kk * N];                  // coalesced across lanes
      const float4* xr = (const float4*)&xs[kk][0];  // wave-uniform broadcast reads
#pragma unroll
      for (int b4 = 0; b4 < 8; ++b4) {
        float4 xv = xr[b4];
        acc[b4 * 4 + 0] += xv.x * w;
        acc[b4 * 4 + 1] += xv.y * w;
        acc[b4 * 4 + 2] += xv.z * w;
        acc[b4 * 4 + 3] += xv.w * w;
      }
    }
  }

  float* pp = part + (size_t)kc * B * N + f;
#pragma unroll
  for (int b = 0; b < B; ++b) pp[(size_t)b * N] = acc[b];
}

// ---------------------------------------------------------------------------
// Reduce split-K partials: out[idx] = sum_kc part[kc][idx]
// ---------------------------------------------------------------------------
__global__ __launch_bounds__(256)
void reduce_partials(const float* __restrict__ part, float* __restrict__ out,
                     int total) {
  int idx = blockIdx.x * 256 + threadIdx.x;
  if (idx >= total) return;
  float s = 0.f;
#pragma unroll
  for (int kc = 0; kc < KS; ++kc) s += part[(size_t)kc * total + idx];
  out[idx] = s;
}

// ---------------------------------------------------------------------------
// Rotary: per (b, head) vector v (128), out[e] = sum_d v[d] * rot[d][e]
// heads 0..31 -> q, scaled by (1/sqrt(128)) * log2(e) so that later
// exp2(q.k) == exp((q.k)/sqrt(128)); heads 32..39 -> k (unscaled).
// ---------------------------------------------------------------------------
__global__ __launch_bounds__(128)
void rotary_kernel(const float* __restrict__ xqkv, const float* __restrict__ rot,
                   float* __restrict__ qrot, float* __restrict__ krot) {
  const int b = blockIdx.x;
  const int h = blockIdx.y;   // 0..39
  const int e = threadIdx.x;  // 0..127

  __shared__ float vec[HD];
  vec[e] = xqkv[(size_t)b * NQKV + h * HD + e];
  __syncthreads();

  float s = 0.f;
#pragma unroll 8
  for (int d = 0; d < HD; ++d) s += vec[d] * rot[d * HD + e];

  const float QSCALE = 0.08838834764831845f * 1.4426950408889634f; // rsqrt(128)*log2(e)
  if (h < NH) {
    qrot[((size_t)b * NH + h) * HD + e] = s * QSCALE;
  } else {
    krot[((size_t)b * NKV + (h - NH)) * HD + e] = s;
  }
}

// ---------------------------------------------------------------------------
// Flash-decode attention partial (fixed-base softmax: no running max).
// Grid (B*NKV pairs, SPLIT chunks), block 256. Half-wave (32 lanes) owns one
// position: coalesced float4 K/V rows. Main loop runs on (possibly stale)
// cache; the new-token substitution at position `cur` is corrected once after
// the loop by the owning half-wave.
// ---------------------------------------------------------------------------
__global__ __launch_bounds__(256)
void attn_partial(const float* __restrict__ cache_k, const float* __restrict__ cache_v,
                  const float* __restrict__ qrot, const float* __restrict__ krot,
                  const float* __restrict__ xqkv, const int* __restrict__ start_pos,
                  float* __restrict__ o_part, float* __restrict__ l_part) {
  const int pair = blockIdx.x;            // b * NKV + kvh
  const int b    = pair >> 3;
  const int kvh  = pair & 7;
  const int chunk = blockIdx.y;

  const int sp    = start_pos[0];
  const int cur   = sp & (WIN - 1);
  const int slice = (sp + 1 < WIN) ? (sp + 1) : WIN;

  const int tid  = threadIdx.x;
  const int wave = tid >> 6;
  const int lane = tid & 63;
  const int half = lane >> 5;
  const int l32  = lane & 31;
  const int hw   = wave * 2 + half;       // half-wave id 0..7

  // q fragments: lane holds d = l32*4 .. l32*4+3 for each of 4 group heads
  float4 q[GRP];
#pragma unroll
  for (int g = 0; g < GRP; ++g)
    q[g] = *(const float4*)(qrot + ((size_t)(b * NH + kvh * GRP + g)) * HD + l32 * 4);

  const float4* kbase = (const float4*)(cache_k + ((size_t)(kvh * B + b)) * WIN * HD);
  const float4* vbase = (const float4*)(cache_v + ((size_t)(kvh * B + b)) * WIN * HD);

  float  l[GRP] = {0.f, 0.f, 0.f, 0.f};
  float4 acc[GRP] = {};

  const int s0 = chunk * SCHUNK;
  int rem = slice - s0 - hw;
  int n_i = rem <= 0 ? 0 : ((rem + 7) >> 3);
  if (n_i > SCHUNK / 8) n_i = SCHUNK / 8;

#pragma unroll 2
  for (int i = 0; i < n_i; ++i) {
    const int p = s0 + i * 8 + hw;
    float4 k4 = kbase[(size_t)p * 32 + l32];
    float4 v4 = vbase[(size_t)p * 32 + l32];

    float s[GRP];
#pragma unroll
    for (int g = 0; g < GRP; ++g)
      s[g] = q[g].x * k4.x + q[g].y * k4.y + q[g].z * k4.z + q[g].w * k4.w;

    // reduce over the 32 lanes of the half-wave
#pragma unroll
    for (int off = 16; off > 0; off >>= 1) {
#pragma unroll
      for (int g = 0; g < GRP; ++g) s[g] += __shfl_xor(s[g], off);
    }

#pragma unroll
    for (int g = 0; g < GRP; ++g) {
      float w = exp2f(s[g]);               // == exp(q.k/sqrt(128)); scale folded in q
      l[g] += w;
      acc[g].x += w * v4.x; acc[g].y += w * v4.y;
      acc[g].z += w * v4.z; acc[g].w += w * v4.w;
    }
  }

  // Correct the new-token position: subtract stale contribution, add new one.
  if (chunk == (cur >> 9) && hw == (cur & 7)) {
    float4 kst = kbase[(size_t)cur * 32 + l32];
    float4 vst = vbase[(size_t)cur * 32 + l32];
    const float4 knew = *(const float4*)(krot + ((size_t)(b * NKV + kvh)) * HD + l32 * 4);
    const float4 vnew = *(const float4*)(xqkv + (size_t)b * NQKV + (NH + NKV + kvh) * HD + l32 * 4);
    float sst[GRP], snw[GRP];
#pragma unroll
    for (int g = 0; g < GRP; ++g) {
      sst[g] = q[g].x * kst.x + q[g].y * kst.y + q[g].z * kst.z + q[g].w * kst.w;
      snw[g] = q[g].x * knew.x + q[g].y * knew.y + q[g].z * knew.z + q[g].w * knew.w;
    }
#pragma unroll
    for (int off = 16; off > 0; off >>= 1) {
#pragma unroll
      for (int g = 0; g < GRP; ++g) {
        sst[g] += __shfl_xor(sst[g], off);
        snw[g] += __shfl_xor(snw[g], off);
      }
    }
#pragma unroll
    for (int g = 0; g < GRP; ++g) {
      float wst = exp2f(sst[g]);
      float wnw = exp2f(snw[g]);
      l[g] += wnw - wst;
      acc[g].x += wnw * vnew.x - wst * vst.x;
      acc[g].y += wnw * vnew.y - wst * vst.y;
      acc[g].z += wnw * vnew.z - wst * vst.z;
      acc[g].w += wnw * vnew.w - wst * vst.w;
    }
  }

  // combine the two halves of the wave (plain adds — no max bookkeeping)
#pragma unroll
  for (int g = 0; g < GRP; ++g) {
    l[g] += __shfl_xor(l[g], 32);
    acc[g].x += __shfl_xor(acc[g].x, 32);
    acc[g].y += __shfl_xor(acc[g].y, 32);
    acc[g].z += __shfl_xor(acc[g].z, 32);
    acc[g].w += __shfl_xor(acc[g].w, 32);
  }

  // combine the 4 waves via LDS
  __shared__ float red_l[4][GRP];
  __shared__ float red_o[4][GRP][HD];
  if (lane == 0) {
#pragma unroll
    for (int g = 0; g < GRP; ++g) red_l[wave][g] = l[g];
  }
  if (half == 0) {
#pragma unroll
    for (int g = 0; g < GRP; ++g)
      *(float4*)&red_o[wave][g][l32 * 4] = acc[g];
  }
  __syncthreads();

  const size_t pc = (size_t)pair * SPLIT + chunk;
  for (int idx = tid; idx < GRP * HD; idx += 256) {
    int g = idx >> 7, d = idx & 127;
    float o = red_o[0][g][d] + red_o[1][g][d] + red_o[2][g][d] + red_o[3][g][d];
    o_part[(pc * GRP + g) * HD + d] = o;
  }
  if (tid < GRP) {
    l_part[pc * GRP + tid] =
        red_l[0][tid] + red_l[1][tid] + red_l[2][tid] + red_l[3][tid];
  }
}

// ---------------------------------------------------------------------------
// Combine the SPLIT chunk partials -> attn_out[b][n*128 + d]
// Grid: B*NH blocks, 128 threads (one per d). Plain sums (fixed-base softmax).
// ---------------------------------------------------------------------------
__global__ __launch_bounds__(128)
void attn_combine(const float* __restrict__ o_part, const float* __restrict__ l_part,
                  float* __restrict__ attn_out) {
  const int bid = blockIdx.x;   // b*32 + n
  const int b = bid >> 5, n = bid & 31;
  const int pair = b * NKV + (n >> 2);
  const int g = n & 3;
  const int d = threadIdx.x;

  float lsum = 0.f, osum = 0.f;
#pragma unroll
  for (int c = 0; c < SPLIT; ++c) {
    size_t pc = (size_t)pair * SPLIT + c;
    lsum += l_part[pc * GRP + g];
    osum += o_part[(pc * GRP + g) * HD + d];
  }
  attn_out[(size_t)b * DIM + n * HD + d] = osum / lsum;
}

// ---------------------------------------------------------------------------
extern "C" void kernel_launch(void* const* d_in, const int* in_sizes, int n_in,
                              void* d_out, int out_size, void* d_ws, size_t ws_size,
                              hipStream_t stream) {
  (void)in_sizes; (void)n_in; (void)out_size; (void)ws_size;

  const float* x    = (const float*)d_in[0];  // [1,1,32,4096]
  const float* wqkv = (const float*)d_in[1];  // [4096,6144]
  const float* wo   = (const float*)d_in[2];  // [4096,4096]
  const float* rot  = (const float*)d_in[3];  // [128,128]
  const float* ck   = (const float*)d_in[4];  // [8,32,4096,128]
  const float* cv   = (const float*)d_in[5];  // [8,32,4096,128]
  const int*   sp   = (const int*)d_in[6];    // scalar
  float* out = (float*)d_out;                 // [32,4096]

  float* ws       = (float*)d_ws;
  float* part     = ws;                                    // KS*B*NQKV = 6,291,456
  float* xqkv     = part + (size_t)KS * B * NQKV;          // 196,608
  float* qrot     = xqkv + (size_t)B * NQKV;               // 131,072
  float* krot     = qrot + (size_t)B * NH * HD;            // 32,768
  float* o_part   = krot + (size_t)B * NKV * HD;           // 1,048,576
  float* l_part   = o_part + (size_t)B * NKV * SPLIT * GRP * HD;   // 8,192
  float* attn_out = l_part + (size_t)B * NKV * SPLIT * GRP;        // 131,072
  // total ~7.8M floats = ~31 MB of workspace

  // 1) xqkv = x @ wqkv  (split-K partials, then reduce)
  gemv32_partial<<<dim3(NQKV / 256, KS), 256, 0, stream>>>(x, wqkv, part, DIM, NQKV);
  reduce_partials<<<(B * NQKV) / 256, 256, 0, stream>>>(part, xqkv, B * NQKV);

  // 2) rotary on q (scaled; exp2 base folded in) and k
  rotary_kernel<<<dim3(B, NH + NKV), 128, 0, stream>>>(xqkv, rot, qrot, krot);

  // 3) flash-decode attention over the KV cache (stale loop + post-correction)
  attn_partial<<<dim3(B * NKV, SPLIT), 256, 0, stream>>>(ck, cv, qrot, krot, xqkv,
                                                         sp, o_part, l_part);
  attn_combine<<<B * NH, 128, 0, stream>>>(o_part, l_part, attn_out);

  // 4) dense = attn_out @ wo
  gemv32_partial<<<dim3(DIM / 256, KS), 256, 0, stream>>>(attn_out, wo, part, DIM, DIM);
  reduce_partials<<<(B * DIM) / 256, 256, 0, stream>>>(part, out, B * DIM);
}